// Round 2
// baseline (280.184 us; speedup 1.0000x reference)
//
#include <hip/hip_runtime.h>
#include <hip/hip_bf16.h>

typedef unsigned short u16;
typedef __attribute__((ext_vector_type(8))) short bf16x8;
typedef __attribute__((ext_vector_type(4))) float f32x4;

#define N 256
#define D 128
#define NH 4
#define KD 32
#define NN 65536
#define QK_SCALE 0.17677669529663687f
#define HUGE_MASK 32768.0f

__device__ __forceinline__ float b2f(u16 s) {
  union { float f; unsigned u; } x; x.u = ((unsigned)s) << 16; return x.f;
}
__device__ __forceinline__ u16 f2b(float f) {
  union { float f; unsigned u; } x; x.f = f;
  unsigned r = x.u + 0x7fff + ((x.u >> 16) & 1);
  return (u16)(r >> 16);
}

// ---------------- Kernel 0: round the 5 big weight matrices fp32 -> bf16 ----
// wb layout: [wq | wk | wv | wg | wo], each 128*128 u16.
__global__ __launch_bounds__(256) void prep_w_kernel(
    const float* __restrict__ wq, const float* __restrict__ wk,
    const float* __restrict__ wv, const float* __restrict__ wg,
    const float* __restrict__ wo, u16* __restrict__ wb)
{
  int idx = blockIdx.x * 256 + threadIdx.x;  // 0 .. 81920
  const float* srcs[5] = {wq, wk, wv, wg, wo};
  int mat = idx >> 14, off = idx & 16383;
  wb[idx] = f2b(srcs[mat][off]);
}

// ---------------- Kernel 1: LayerNorm (fp32 in, bf16 x out) + nb ----------------
// 1 wave per position; lane holds 2 of the 128 channels.
__global__ __launch_bounds__(256) void ln_nb_kernel(
    const float* __restrict__ pa, const float* __restrict__ lns, const float* __restrict__ lnb,
    const float* __restrict__ w2d, u16* __restrict__ x, float* __restrict__ nb)
{
  int wave = threadIdx.x >> 6, lane = threadIdx.x & 63;
  int pos = blockIdx.x * 4 + wave;
  const float* row = pa + (size_t)pos * D;
  float2 rv = *(const float2*)(row + 2 * lane);
  float v0 = rv.x, v1 = rv.y;
  float s = v0 + v1, ss = v0 * v0 + v1 * v1;
#pragma unroll
  for (int off = 32; off; off >>= 1) {
    s  += __shfl_xor(s, off, 64);
    ss += __shfl_xor(ss, off, 64);
  }
  float mu = s * (1.0f / D);
  float var = ss * (1.0f / D) - mu * mu;
  float rs = rsqrtf(var + 1e-5f);
  float2 sv = *(const float2*)(lns + 2 * lane);
  float2 bv = *(const float2*)(lnb + 2 * lane);
  float x0 = (v0 - mu) * rs * sv.x + bv.x;
  float x1 = (v1 - mu) * rs * sv.y + bv.y;
  unsigned outpack = (unsigned)f2b(x0) | ((unsigned)f2b(x1) << 16);
  *(unsigned*)(x + (size_t)pos * D + 2 * lane) = outpack;
  float dh[NH];
#pragma unroll
  for (int h = 0; h < NH; h++) {
    float2 wv2 = *(const float2*)(w2d + h * D + 2 * lane);
    float p = x0 * wv2.x + x1 * wv2.y;
#pragma unroll
    for (int off = 32; off; off >>= 1) p += __shfl_xor(p, off, 64);
    dh[h] = p;
  }
  if (lane == 0) {
#pragma unroll
    for (int h = 0; h < NH; h++) nb[(size_t)h * NN + pos] = dh[h];
  }
}

// ---------------- Kernel 2: q,k,v,g projections (MFMA GEMM) ----------------
// Block: 256 thr (4 waves). Tile M=64 (16/wave), N=128, K=128. 4 weight mats.
__global__ __launch_bounds__(256) void proj_kernel(
    const u16* __restrict__ x, const u16* __restrict__ wb, const float* __restrict__ bg,
    u16* __restrict__ q, u16* __restrict__ k, u16* __restrict__ v, u16* __restrict__ g)
{
  int wave = threadIdx.x >> 6, lane = threadIdx.x & 63;
  int lr = lane & 15, quad = lane >> 4;
  int arow = blockIdx.x * 64 + wave * 16 + lr;
  int k0 = quad * 8;
  bf16x8 a[4];
#pragma unroll
  for (int ks = 0; ks < 4; ks++)
    a[ks] = *(const bf16x8*)(x + (size_t)arow * D + ks * 32 + k0);

  u16* Os[4] = {q, k, v, g};
  int row0 = blockIdx.x * 64 + wave * 16 + quad * 4;
#pragma unroll
  for (int mat = 0; mat < 4; mat++) {
    const u16* W = wb + (size_t)mat * D * D;
    f32x4 acc[8];
#pragma unroll
    for (int t = 0; t < 8; t++) acc[t] = (f32x4){0.f, 0.f, 0.f, 0.f};
#pragma unroll
    for (int ks = 0; ks < 4; ks++) {
#pragma unroll
      for (int t = 0; t < 8; t++) {
        bf16x8 b = *(const bf16x8*)(W + (size_t)(t * 16 + lr) * D + ks * 32 + k0);
        acc[t] = __builtin_amdgcn_mfma_f32_16x16x32_bf16(a[ks], b, acc[t], 0, 0, 0);
      }
    }
    u16* O = Os[mat];
#pragma unroll
    for (int t = 0; t < 8; t++) {
      int c = t * 16 + lr;
      float bgc = (mat == 3) ? bg[c] : 0.0f;
#pragma unroll
      for (int r = 0; r < 4; r++) {
        float val = acc[t][r];
        if (mat == 0) val *= QK_SCALE;
        if (mat == 3) val = 1.0f / (1.0f + __expf(-(val + bgc)));
        O[(size_t)(row0 + r) * D + c] = f2b(val);
      }
    }
  }
}

// ---------------- Kernel 3: attention per (r, h) ----------------
#define KSTRIDE 40
#define VSTRIDE 264
#define PSTRIDE 264
__global__ __launch_bounds__(256) void attn_kernel(
    const u16* __restrict__ q, const u16* __restrict__ k, const u16* __restrict__ v,
    const u16* __restrict__ g, const float* __restrict__ nb, const float* __restrict__ mask,
    u16* __restrict__ og)
{
  __shared__ __align__(16) u16 Kt[256 * KSTRIDE];
  __shared__ __align__(16) u16 Vt[32 * VSTRIDE];
  __shared__ __align__(16) u16 P[4 * 16 * PSTRIDE];
  int h = blockIdx.x & 3, r = blockIdx.x >> 2;
  int tid = threadIdx.x;
  {
    const u16* krow = k + ((size_t)r * N + tid) * D + h * KD;
#pragma unroll
    for (int ii = 0; ii < 4; ii++)
      *(bf16x8*)(&Kt[tid * KSTRIDE + ii * 8]) = *(const bf16x8*)(krow + ii * 8);
    const u16* vrow = v + ((size_t)r * N + tid) * D + h * KD;
#pragma unroll
    for (int c = 0; c < KD; c++)
      Vt[c * VSTRIDE + tid] = vrow[c];
  }
  __syncthreads();
  int wave = tid >> 6, lane = tid & 63;
  int lr = lane & 15, quad = lane >> 4;
  u16* Pw = &P[wave * 16 * PSTRIDE];

  for (int pass = 0; pass < 4; pass++) {
    int i0 = pass * 64 + wave * 16;
    bf16x8 af = *(const bf16x8*)(q + ((size_t)r * N + i0 + lr) * D + h * KD + quad * 8);
    f32x4 S[16];
#pragma unroll
    for (int t = 0; t < 16; t++) {
      bf16x8 bfr = *(const bf16x8*)(&Kt[(t * 16 + lr) * KSTRIDE + quad * 8]);
      S[t] = __builtin_amdgcn_mfma_f32_16x16x32_bf16(af, bfr, (f32x4){0.f,0.f,0.f,0.f}, 0, 0, 0);
    }
    float mx[4] = {-3e38f, -3e38f, -3e38f, -3e38f};
#pragma unroll
    for (int t = 0; t < 16; t++) {
      int j = t * 16 + lr;
      float bias = HUGE_MASK * (mask[r * N + j] - 1.0f);
      const float* nbp = &nb[(size_t)h * NN + (size_t)(i0 + quad * 4) * N + j];
#pragma unroll
      for (int reg = 0; reg < 4; reg++) {
        float val = S[t][reg] + bias + nbp[(size_t)reg * N];
        S[t][reg] = val;
        mx[reg] = fmaxf(mx[reg], val);
      }
    }
#pragma unroll
    for (int reg = 0; reg < 4; reg++) {
#pragma unroll
      for (int off = 8; off; off >>= 1)
        mx[reg] = fmaxf(mx[reg], __shfl_xor(mx[reg], off, 16));
    }
    float lsum[4] = {0.f, 0.f, 0.f, 0.f};
#pragma unroll
    for (int t = 0; t < 16; t++) {
#pragma unroll
      for (int reg = 0; reg < 4; reg++) {
        float p = __expf(S[t][reg] - mx[reg]);
        S[t][reg] = p;
        lsum[reg] += p;
      }
    }
#pragma unroll
    for (int reg = 0; reg < 4; reg++) {
#pragma unroll
      for (int off = 8; off; off >>= 1)
        lsum[reg] += __shfl_xor(lsum[reg], off, 16);
    }
#pragma unroll
    for (int t = 0; t < 16; t++) {
#pragma unroll
      for (int reg = 0; reg < 4; reg++)
        Pw[(quad * 4 + reg) * PSTRIDE + t * 16 + lr] = f2b(S[t][reg]);
    }
    __syncthreads();  // drain LDS writes before fragment reads
    f32x4 o[2] = {(f32x4){0.f,0.f,0.f,0.f}, (f32x4){0.f,0.f,0.f,0.f}};
#pragma unroll
    for (int ks = 0; ks < 8; ks++) {
      bf16x8 pa = *(const bf16x8*)(&Pw[lr * PSTRIDE + ks * 32 + quad * 8]);
#pragma unroll
      for (int u = 0; u < 2; u++) {
        bf16x8 vb = *(const bf16x8*)(&Vt[(u * 16 + lr) * VSTRIDE + ks * 32 + quad * 8]);
        o[u] = __builtin_amdgcn_mfma_f32_16x16x32_bf16(pa, vb, o[u], 0, 0, 0);
      }
    }
#pragma unroll
    for (int u = 0; u < 2; u++) {
#pragma unroll
      for (int reg = 0; reg < 4; reg++) {
        int i = i0 + quad * 4 + reg;
        int c = h * KD + u * 16 + lr;
        size_t idx = ((size_t)r * N + i) * D + c;
        float val = o[u][reg] / lsum[reg] * b2f(g[idx]);
        og[idx] = f2b(val);
      }
    }
  }
}

// ---------------- Kernel 4: output projection + bias + mask (fp32 out) -------
__global__ __launch_bounds__(256) void out_kernel(
    const u16* __restrict__ og, const u16* __restrict__ wob, const float* __restrict__ bo,
    const float* __restrict__ mask, float* __restrict__ out)
{
  int wave = threadIdx.x >> 6, lane = threadIdx.x & 63;
  int lr = lane & 15, quad = lane >> 4;
  int arow = blockIdx.x * 64 + wave * 16 + lr;
  int k0 = quad * 8;
  bf16x8 a[4];
#pragma unroll
  for (int ks = 0; ks < 4; ks++)
    a[ks] = *(const bf16x8*)(og + (size_t)arow * D + ks * 32 + k0);
  f32x4 acc[8];
#pragma unroll
  for (int t = 0; t < 8; t++) acc[t] = (f32x4){0.f, 0.f, 0.f, 0.f};
#pragma unroll
  for (int ks = 0; ks < 4; ks++) {
#pragma unroll
    for (int t = 0; t < 8; t++) {
      bf16x8 b = *(const bf16x8*)(wob + (size_t)(t * 16 + lr) * D + ks * 32 + k0);
      acc[t] = __builtin_amdgcn_mfma_f32_16x16x32_bf16(a[ks], b, acc[t], 0, 0, 0);
    }
  }
  int row0 = blockIdx.x * 64 + wave * 16 + quad * 4;
#pragma unroll
  for (int t = 0; t < 8; t++) {
    int c = t * 16 + lr;
    float boc = bo[c];
#pragma unroll
    for (int r = 0; r < 4; r++) {
      int pos = row0 + r;
      float val = (acc[t][r] + boc) * mask[pos];
      out[(size_t)pos * D + c] = val;
    }
  }
}

extern "C" void kernel_launch(void* const* d_in, const int* in_sizes, int n_in,
                              void* d_out, int out_size, void* d_ws, size_t ws_size,
                              hipStream_t stream)
{
  const float* pa   = (const float*)d_in[0];
  const float* mask = (const float*)d_in[1];
  const float* lns  = (const float*)d_in[2];
  const float* lnb  = (const float*)d_in[3];
  const float* w2d  = (const float*)d_in[4];
  const float* wq   = (const float*)d_in[5];
  const float* wk   = (const float*)d_in[6];
  const float* wv   = (const float*)d_in[7];
  const float* wg   = (const float*)d_in[8];
  const float* bg   = (const float*)d_in[9];
  const float* wo   = (const float*)d_in[10];
  const float* bo   = (const float*)d_in[11];

  const size_t ARR = (size_t)NN * D;     // 8M elements
  u16* x  = (u16*)d_ws;
  u16* q  = x + ARR;
  u16* k  = q + ARR;
  u16* v  = k + ARR;
  u16* g  = v + ARR;
  u16* og = g + ARR;
  float* nb = (float*)(og + ARR);        // NH*NN floats = 1 MB
  u16* wb = (u16*)(nb + (size_t)NH * NN); // 5*128*128 u16

  prep_w_kernel<<<320, 256, 0, stream>>>(wq, wk, wv, wg, wo, wb);
  ln_nb_kernel<<<NN / 4, 256, 0, stream>>>(pa, lns, lnb, w2d, x, nb);
  proj_kernel<<<NN / 64, 256, 0, stream>>>(x, wb, bg, q, k, v, g);
  attn_kernel<<<N * NH, 256, 0, stream>>>(q, k, v, g, nb, mask, og);
  out_kernel<<<NN / 64, 256, 0, stream>>>(og, wb + 4 * (size_t)D * D, bo, mask, (float*)d_out);
}

// Round 3
// 261.614 us; speedup vs baseline: 1.0710x; 1.0710x over previous
//
#include <hip/hip_runtime.h>
#include <hip/hip_bf16.h>

typedef unsigned short u16;
typedef __attribute__((ext_vector_type(8))) short bf16x8;
typedef __attribute__((ext_vector_type(4))) float f32x4;

#define N 256
#define D 128
#define NH 4
#define KD 32
#define NN 65536
#define QK_SCALE 0.17677669529663687f
#define HUGE_MASK 32768.0f

__device__ __forceinline__ float b2f(u16 s) {
  union { float f; unsigned u; } x; x.u = ((unsigned)s) << 16; return x.f;
}
__device__ __forceinline__ u16 f2b(float f) {
  union { float f; unsigned u; } x; x.f = f;
  unsigned r = x.u + 0x7fff + ((x.u >> 16) & 1);
  return (u16)(r >> 16);
}

// ---------------- Kernel 0: round the 5 big weight matrices fp32 -> bf16 ----
// wb layout: [wq | wk | wv | wg | wo], each 128*128 u16.
__global__ __launch_bounds__(256) void prep_w_kernel(
    const float* __restrict__ wq, const float* __restrict__ wk,
    const float* __restrict__ wv, const float* __restrict__ wg,
    const float* __restrict__ wo, u16* __restrict__ wb)
{
  int idx = blockIdx.x * 256 + threadIdx.x;  // 0 .. 81920
  const float* srcs[5] = {wq, wk, wv, wg, wo};
  int mat = idx >> 14, off = idx & 16383;
  wb[idx] = f2b(srcs[mat][off]);
}

// ---------------- Kernel 1: fused LayerNorm + nb + q,k,v,g projections ------
// Block: 256 thr (4 waves). M=64 rows/block (16/wave). A-frags built in-reg
// from fp32 pa with LN applied; row stats via quad shuffles (row = lane&15,
// channels split across the 4 quad-lanes).
// Packed-store column remap: n-tile (tg,e) covers col = tg*64 + 4*lr + e, so
// each lane owns 4 adjacent columns -> 8-B uint2 stores (128-B segments).
__global__ __launch_bounds__(256) void projln_kernel(
    const float* __restrict__ pa, const float* __restrict__ lns, const float* __restrict__ lnb,
    const float* __restrict__ w2d, const u16* __restrict__ wb, const float* __restrict__ bg,
    u16* __restrict__ q, u16* __restrict__ k, u16* __restrict__ v, u16* __restrict__ g,
    float* __restrict__ nb)
{
  int wave = threadIdx.x >> 6, lane = threadIdx.x & 63;
  int lr = lane & 15, quad = lane >> 4;
  int row = blockIdx.x * 64 + wave * 16 + lr;   // this lane's A-row
  const float* rp = pa + (size_t)row * D;

  // load this lane's 32 channels (4 ks-slices of 8), accumulate stats
  float xv[4][8];
  float s = 0.f, ss = 0.f;
#pragma unroll
  for (int ks = 0; ks < 4; ks++) {
    float4 a0 = *(const float4*)(rp + ks * 32 + quad * 8);
    float4 a1 = *(const float4*)(rp + ks * 32 + quad * 8 + 4);
    xv[ks][0] = a0.x; xv[ks][1] = a0.y; xv[ks][2] = a0.z; xv[ks][3] = a0.w;
    xv[ks][4] = a1.x; xv[ks][5] = a1.y; xv[ks][6] = a1.z; xv[ks][7] = a1.w;
#pragma unroll
    for (int j = 0; j < 8; j++) { s += xv[ks][j]; ss += xv[ks][j] * xv[ks][j]; }
  }
  // reduce across the 4 quad-lanes holding this row
  s  += __shfl_xor(s, 16, 64);  ss += __shfl_xor(ss, 16, 64);
  s  += __shfl_xor(s, 32, 64);  ss += __shfl_xor(ss, 32, 64);
  float mu = s * (1.0f / D);
  float var = ss * (1.0f / D) - mu * mu;
  float rs = rsqrtf(var + 1e-5f);

  // apply LN scale/bias (fp32)
#pragma unroll
  for (int ks = 0; ks < 4; ks++) {
    float4 s0 = *(const float4*)(lns + ks * 32 + quad * 8);
    float4 s1 = *(const float4*)(lns + ks * 32 + quad * 8 + 4);
    float4 b0 = *(const float4*)(lnb + ks * 32 + quad * 8);
    float4 b1 = *(const float4*)(lnb + ks * 32 + quad * 8 + 4);
    float sc[8] = {s0.x,s0.y,s0.z,s0.w,s1.x,s1.y,s1.z,s1.w};
    float bi[8] = {b0.x,b0.y,b0.z,b0.w,b1.x,b1.y,b1.z,b1.w};
#pragma unroll
    for (int j = 0; j < 8; j++) xv[ks][j] = (xv[ks][j] - mu) * rs * sc[j] + bi[j];
  }

  // nb[h, row] = x . w2d[h]  (fp32)
#pragma unroll
  for (int h = 0; h < NH; h++) {
    float p = 0.f;
#pragma unroll
    for (int ks = 0; ks < 4; ks++) {
      float4 w0 = *(const float4*)(w2d + h * D + ks * 32 + quad * 8);
      float4 w1 = *(const float4*)(w2d + h * D + ks * 32 + quad * 8 + 4);
      p += xv[ks][0]*w0.x + xv[ks][1]*w0.y + xv[ks][2]*w0.z + xv[ks][3]*w0.w
         + xv[ks][4]*w1.x + xv[ks][5]*w1.y + xv[ks][6]*w1.z + xv[ks][7]*w1.w;
    }
    p += __shfl_xor(p, 16, 64);
    p += __shfl_xor(p, 32, 64);
    if (quad == 0) nb[(size_t)h * NN + row] = p;
  }

  // pack A-fragments (bf16)
  bf16x8 a[4];
#pragma unroll
  for (int ks = 0; ks < 4; ks++) {
#pragma unroll
    for (int j = 0; j < 8; j++) a[ks][j] = (short)f2b(xv[ks][j]);
  }

  u16* Os[4] = {q, k, v, g};
  int row0 = blockIdx.x * 64 + wave * 16 + quad * 4;
#pragma unroll
  for (int mat = 0; mat < 4; mat++) {
    const u16* W = wb + (size_t)mat * D * D;
    f32x4 acc[2][4];
#pragma unroll
    for (int tg = 0; tg < 2; tg++)
#pragma unroll
      for (int e = 0; e < 4; e++) acc[tg][e] = (f32x4){0.f, 0.f, 0.f, 0.f};
#pragma unroll
    for (int ks = 0; ks < 4; ks++) {
#pragma unroll
      for (int tg = 0; tg < 2; tg++) {
#pragma unroll
        for (int e = 0; e < 4; e++) {
          bf16x8 b = *(const bf16x8*)(W + (size_t)(tg * 64 + 4 * lr + e) * D + ks * 32 + quad * 8);
          acc[tg][e] = __builtin_amdgcn_mfma_f32_16x16x32_bf16(a[ks], b, acc[tg][e], 0, 0, 0);
        }
      }
    }
    u16* O = Os[mat];
#pragma unroll
    for (int tg = 0; tg < 2; tg++) {
      int c0 = tg * 64 + 4 * lr;
      float bg0 = 0.f, bg1 = 0.f, bg2 = 0.f, bg3 = 0.f;
      if (mat == 3) { bg0 = bg[c0]; bg1 = bg[c0+1]; bg2 = bg[c0+2]; bg3 = bg[c0+3]; }
#pragma unroll
      for (int reg = 0; reg < 4; reg++) {
        float v0 = acc[tg][0][reg], v1 = acc[tg][1][reg];
        float v2 = acc[tg][2][reg], v3 = acc[tg][3][reg];
        if (mat == 0) { v0 *= QK_SCALE; v1 *= QK_SCALE; v2 *= QK_SCALE; v3 *= QK_SCALE; }
        if (mat == 3) {
          v0 = 1.0f / (1.0f + __expf(-(v0 + bg0)));
          v1 = 1.0f / (1.0f + __expf(-(v1 + bg1)));
          v2 = 1.0f / (1.0f + __expf(-(v2 + bg2)));
          v3 = 1.0f / (1.0f + __expf(-(v3 + bg3)));
        }
        uint2 pk;
        pk.x = (unsigned)f2b(v0) | ((unsigned)f2b(v1) << 16);
        pk.y = (unsigned)f2b(v2) | ((unsigned)f2b(v3) << 16);
        *(uint2*)(O + (size_t)(row0 + reg) * D + c0) = pk;
      }
    }
  }
}

// ---------------- Kernel 2: attention per (r, h) ----------------
#define KSTRIDE 40
#define VSTRIDE 264
#define PSTRIDE 264
__global__ __launch_bounds__(256) void attn_kernel(
    const u16* __restrict__ q, const u16* __restrict__ k, const u16* __restrict__ v,
    const u16* __restrict__ g, const float* __restrict__ nb, const float* __restrict__ mask,
    u16* __restrict__ og)
{
  __shared__ __align__(16) u16 Kt[256 * KSTRIDE];
  __shared__ __align__(16) u16 Vt[32 * VSTRIDE];
  __shared__ __align__(16) u16 P[4 * 16 * PSTRIDE];
  int h = blockIdx.x & 3, r = blockIdx.x >> 2;
  int tid = threadIdx.x;
  {
    const u16* krow = k + ((size_t)r * N + tid) * D + h * KD;
#pragma unroll
    for (int ii = 0; ii < 4; ii++)
      *(bf16x8*)(&Kt[tid * KSTRIDE + ii * 8]) = *(const bf16x8*)(krow + ii * 8);
    const u16* vrow = v + ((size_t)r * N + tid) * D + h * KD;
#pragma unroll
    for (int c = 0; c < KD; c++)
      Vt[c * VSTRIDE + tid] = vrow[c];
  }
  __syncthreads();
  int wave = tid >> 6, lane = tid & 63;
  int lr = lane & 15, quad = lane >> 4;
  u16* Pw = &P[wave * 16 * PSTRIDE];

  for (int pass = 0; pass < 4; pass++) {
    int i0 = pass * 64 + wave * 16;
    bf16x8 af = *(const bf16x8*)(q + ((size_t)r * N + i0 + lr) * D + h * KD + quad * 8);
    f32x4 S[16];
#pragma unroll
    for (int t = 0; t < 16; t++) {
      bf16x8 bfr = *(const bf16x8*)(&Kt[(t * 16 + lr) * KSTRIDE + quad * 8]);
      S[t] = __builtin_amdgcn_mfma_f32_16x16x32_bf16(af, bfr, (f32x4){0.f,0.f,0.f,0.f}, 0, 0, 0);
    }
    float mx[4] = {-3e38f, -3e38f, -3e38f, -3e38f};
#pragma unroll
    for (int t = 0; t < 16; t++) {
      int j = t * 16 + lr;
      float bias = HUGE_MASK * (mask[r * N + j] - 1.0f);
      const float* nbp = &nb[(size_t)h * NN + (size_t)(i0 + quad * 4) * N + j];
#pragma unroll
      for (int reg = 0; reg < 4; reg++) {
        float val = S[t][reg] + bias + nbp[(size_t)reg * N];
        S[t][reg] = val;
        mx[reg] = fmaxf(mx[reg], val);
      }
    }
#pragma unroll
    for (int reg = 0; reg < 4; reg++) {
#pragma unroll
      for (int off = 8; off; off >>= 1)
        mx[reg] = fmaxf(mx[reg], __shfl_xor(mx[reg], off, 16));
    }
    float lsum[4] = {0.f, 0.f, 0.f, 0.f};
#pragma unroll
    for (int t = 0; t < 16; t++) {
#pragma unroll
      for (int reg = 0; reg < 4; reg++) {
        float p = __expf(S[t][reg] - mx[reg]);
        S[t][reg] = p;
        lsum[reg] += p;
      }
    }
#pragma unroll
    for (int reg = 0; reg < 4; reg++) {
#pragma unroll
      for (int off = 8; off; off >>= 1)
        lsum[reg] += __shfl_xor(lsum[reg], off, 16);
    }
#pragma unroll
    for (int t = 0; t < 16; t++) {
#pragma unroll
      for (int reg = 0; reg < 4; reg++)
        Pw[(quad * 4 + reg) * PSTRIDE + t * 16 + lr] = f2b(S[t][reg]);
    }
    __syncthreads();  // drain LDS writes before fragment reads
    f32x4 o[2] = {(f32x4){0.f,0.f,0.f,0.f}, (f32x4){0.f,0.f,0.f,0.f}};
#pragma unroll
    for (int ks = 0; ks < 8; ks++) {
      bf16x8 pa = *(const bf16x8*)(&Pw[lr * PSTRIDE + ks * 32 + quad * 8]);
#pragma unroll
      for (int u = 0; u < 2; u++) {
        bf16x8 vb = *(const bf16x8*)(&Vt[(u * 16 + lr) * VSTRIDE + ks * 32 + quad * 8]);
        o[u] = __builtin_amdgcn_mfma_f32_16x16x32_bf16(pa, vb, o[u], 0, 0, 0);
      }
    }
#pragma unroll
    for (int u = 0; u < 2; u++) {
#pragma unroll
      for (int reg = 0; reg < 4; reg++) {
        int i = i0 + quad * 4 + reg;
        int c = h * KD + u * 16 + lr;
        size_t idx = ((size_t)r * N + i) * D + c;
        float val = o[u][reg] / lsum[reg] * b2f(g[idx]);
        og[idx] = f2b(val);
      }
    }
  }
}

// ---------------- Kernel 3: output projection + bias + mask (fp32 out) -------
// Packed-store remap: col = tg*64 + 4*lr + e -> float4 stores (256-B segments).
__global__ __launch_bounds__(256) void out_kernel(
    const u16* __restrict__ og, const u16* __restrict__ wob, const float* __restrict__ bo,
    const float* __restrict__ mask, float* __restrict__ out)
{
  int wave = threadIdx.x >> 6, lane = threadIdx.x & 63;
  int lr = lane & 15, quad = lane >> 4;
  int arow = blockIdx.x * 64 + wave * 16 + lr;
  int k0 = quad * 8;
  bf16x8 a[4];
#pragma unroll
  for (int ks = 0; ks < 4; ks++)
    a[ks] = *(const bf16x8*)(og + (size_t)arow * D + ks * 32 + k0);
  f32x4 acc[2][4];
#pragma unroll
  for (int tg = 0; tg < 2; tg++)
#pragma unroll
    for (int e = 0; e < 4; e++) acc[tg][e] = (f32x4){0.f, 0.f, 0.f, 0.f};
#pragma unroll
  for (int ks = 0; ks < 4; ks++) {
#pragma unroll
    for (int tg = 0; tg < 2; tg++) {
#pragma unroll
      for (int e = 0; e < 4; e++) {
        bf16x8 b = *(const bf16x8*)(wob + (size_t)(tg * 64 + 4 * lr + e) * D + ks * 32 + k0);
        acc[tg][e] = __builtin_amdgcn_mfma_f32_16x16x32_bf16(a[ks], b, acc[tg][e], 0, 0, 0);
      }
    }
  }
  int row0 = blockIdx.x * 64 + wave * 16 + quad * 4;
#pragma unroll
  for (int tg = 0; tg < 2; tg++) {
    int c0 = tg * 64 + 4 * lr;
    float4 bo4 = *(const float4*)(bo + c0);
#pragma unroll
    for (int reg = 0; reg < 4; reg++) {
      int pos = row0 + reg;
      float m = mask[pos];
      float4 o4;
      o4.x = (acc[tg][0][reg] + bo4.x) * m;
      o4.y = (acc[tg][1][reg] + bo4.y) * m;
      o4.z = (acc[tg][2][reg] + bo4.z) * m;
      o4.w = (acc[tg][3][reg] + bo4.w) * m;
      *(float4*)(out + (size_t)pos * D + c0) = o4;
    }
  }
}

extern "C" void kernel_launch(void* const* d_in, const int* in_sizes, int n_in,
                              void* d_out, int out_size, void* d_ws, size_t ws_size,
                              hipStream_t stream)
{
  const float* pa   = (const float*)d_in[0];
  const float* mask = (const float*)d_in[1];
  const float* lns  = (const float*)d_in[2];
  const float* lnb  = (const float*)d_in[3];
  const float* w2d  = (const float*)d_in[4];
  const float* wq   = (const float*)d_in[5];
  const float* wk   = (const float*)d_in[6];
  const float* wv   = (const float*)d_in[7];
  const float* wg   = (const float*)d_in[8];
  const float* bg   = (const float*)d_in[9];
  const float* wo   = (const float*)d_in[10];
  const float* bo   = (const float*)d_in[11];

  const size_t ARR = (size_t)NN * D;     // 8M elements
  u16* q  = (u16*)d_ws;
  u16* k  = q + ARR;
  u16* v  = k + ARR;
  u16* g  = v + ARR;
  u16* og = g + ARR;
  float* nb = (float*)(og + ARR);         // NH*NN floats = 1 MB
  u16* wb = (u16*)(nb + (size_t)NH * NN); // 5*128*128 u16

  prep_w_kernel<<<320, 256, 0, stream>>>(wq, wk, wv, wg, wo, wb);
  projln_kernel<<<NN / 64, 256, 0, stream>>>(pa, lns, lnb, w2d, wb, bg, q, k, v, g, nb);
  attn_kernel<<<N * NH, 256, 0, stream>>>(q, k, v, g, nb, mask, og);
  out_kernel<<<NN / 64, 256, 0, stream>>>(og, wb + 4 * (size_t)D * D, bo, mask, (float*)d_out);
}

// Round 4
// 217.200 us; speedup vs baseline: 1.2900x; 1.2045x over previous
//
#include <hip/hip_runtime.h>
#include <hip/hip_bf16.h>

typedef unsigned short u16;
typedef __attribute__((ext_vector_type(8))) short bf16x8;
typedef __attribute__((ext_vector_type(4))) float f32x4;

#define N 256
#define D 128
#define NH 4
#define KD 32
#define NN 65536
#define QK_SCALE 0.17677669529663687f
#define HUGE_MASK 32768.0f

__device__ __forceinline__ float b2f(u16 s) {
  union { float f; unsigned u; } x; x.u = ((unsigned)s) << 16; return x.f;
}
__device__ __forceinline__ u16 f2b(float f) {
  union { float f; unsigned u; } x; x.f = f;
  unsigned r = x.u + 0x7fff + ((x.u >> 16) & 1);
  return (u16)(r >> 16);
}

// Stage a 128x128 fp32 weight matrix into LDS as bf16 with XOR-rotate swizzle:
// 8-elem group g of row n lands at group gp = (g + (n&15)) & 15.
// 256 threads: thread t covers row t>>1, cols (t&1)*64 .. +63.
__device__ __forceinline__ void stage_w(const float* __restrict__ W, u16* Wlds, int tid) {
  int row = tid >> 1, cb = (tid & 1) * 64;
#pragma unroll
  for (int j = 0; j < 8; j++) {
    float4 f0 = *(const float4*)(W + row * 128 + cb + j * 8);
    float4 f1 = *(const float4*)(W + row * 128 + cb + j * 8 + 4);
    uint4 pk;
    pk.x = (unsigned)f2b(f0.x) | ((unsigned)f2b(f0.y) << 16);
    pk.y = (unsigned)f2b(f0.z) | ((unsigned)f2b(f0.w) << 16);
    pk.z = (unsigned)f2b(f1.x) | ((unsigned)f2b(f1.y) << 16);
    pk.w = (unsigned)f2b(f1.z) | ((unsigned)f2b(f1.w) << 16);
    int g = (cb >> 3) + j;
    int gp = (g + (row & 15)) & 15;
    *(uint4*)(&Wlds[row * 128 + gp * 8]) = pk;
  }
}

// ---------------- Kernel 1: fused LN + nb + q,k,v,g projections --------------
// Grid 512 x 256thr. Block: M=128 rows; wave: 32 rows = 2 m-tiles.
// Weights staged per-mat in LDS (32 KB bf16, swizzled); each B-frag ds_read
// feeds 2 MFMAs. Packed uint2 stores (col = tg*64 + 4*lr + e).
__global__ __launch_bounds__(256) void projln_kernel(
    const float* __restrict__ pa, const float* __restrict__ lns, const float* __restrict__ lnb,
    const float* __restrict__ w2d,
    const float* __restrict__ wq, const float* __restrict__ wk,
    const float* __restrict__ wv, const float* __restrict__ wg,
    const float* __restrict__ bg,
    u16* __restrict__ q, u16* __restrict__ k, u16* __restrict__ v, u16* __restrict__ g,
    float* __restrict__ nb)
{
  __shared__ __align__(16) u16 Wlds[128 * 128];
  int tid = threadIdx.x;
  int wave = tid >> 6, lane = tid & 63;
  int lr = lane & 15, quad = lane >> 4;

  // ---- LN + nb + A-fragments for 2 m-tiles (32 rows/wave) ----
  bf16x8 a[2][4];
#pragma unroll
  for (int mt = 0; mt < 2; mt++) {
    int row = blockIdx.x * 128 + wave * 32 + mt * 16 + lr;
    const float* rp = pa + (size_t)row * D;
    float xv[4][8];
    float s = 0.f, ss = 0.f;
#pragma unroll
    for (int ks = 0; ks < 4; ks++) {
      float4 a0 = *(const float4*)(rp + ks * 32 + quad * 8);
      float4 a1 = *(const float4*)(rp + ks * 32 + quad * 8 + 4);
      xv[ks][0] = a0.x; xv[ks][1] = a0.y; xv[ks][2] = a0.z; xv[ks][3] = a0.w;
      xv[ks][4] = a1.x; xv[ks][5] = a1.y; xv[ks][6] = a1.z; xv[ks][7] = a1.w;
#pragma unroll
      for (int j = 0; j < 8; j++) { s += xv[ks][j]; ss += xv[ks][j] * xv[ks][j]; }
    }
    s  += __shfl_xor(s, 16, 64);  ss += __shfl_xor(ss, 16, 64);
    s  += __shfl_xor(s, 32, 64);  ss += __shfl_xor(ss, 32, 64);
    float mu = s * (1.0f / D);
    float var = ss * (1.0f / D) - mu * mu;
    float rs = rsqrtf(var + 1e-5f);
#pragma unroll
    for (int ks = 0; ks < 4; ks++) {
      float4 s0 = *(const float4*)(lns + ks * 32 + quad * 8);
      float4 s1 = *(const float4*)(lns + ks * 32 + quad * 8 + 4);
      float4 b0 = *(const float4*)(lnb + ks * 32 + quad * 8);
      float4 b1 = *(const float4*)(lnb + ks * 32 + quad * 8 + 4);
      float sc[8] = {s0.x,s0.y,s0.z,s0.w,s1.x,s1.y,s1.z,s1.w};
      float bi[8] = {b0.x,b0.y,b0.z,b0.w,b1.x,b1.y,b1.z,b1.w};
#pragma unroll
      for (int j = 0; j < 8; j++) xv[ks][j] = (xv[ks][j] - mu) * rs * sc[j] + bi[j];
    }
#pragma unroll
    for (int h = 0; h < NH; h++) {
      float p = 0.f;
#pragma unroll
      for (int ks = 0; ks < 4; ks++) {
        float4 w0 = *(const float4*)(w2d + h * D + ks * 32 + quad * 8);
        float4 w1 = *(const float4*)(w2d + h * D + ks * 32 + quad * 8 + 4);
        p += xv[ks][0]*w0.x + xv[ks][1]*w0.y + xv[ks][2]*w0.z + xv[ks][3]*w0.w
           + xv[ks][4]*w1.x + xv[ks][5]*w1.y + xv[ks][6]*w1.z + xv[ks][7]*w1.w;
      }
      p += __shfl_xor(p, 16, 64);
      p += __shfl_xor(p, 32, 64);
      if (quad == 0) nb[(size_t)h * NN + row] = p;
    }
#pragma unroll
    for (int ks = 0; ks < 4; ks++)
#pragma unroll
      for (int j = 0; j < 8; j++) a[mt][ks][j] = (short)f2b(xv[ks][j]);
  }

  const float* Ws[4] = {wq, wk, wv, wg};
  u16* Os[4] = {q, k, v, g};
#pragma unroll
  for (int mat = 0; mat < 4; mat++) {
    stage_w(Ws[mat], Wlds, tid);
    __syncthreads();
    f32x4 acc[2][2][4];
#pragma unroll
    for (int mt = 0; mt < 2; mt++)
#pragma unroll
      for (int tg = 0; tg < 2; tg++)
#pragma unroll
        for (int e = 0; e < 4; e++) acc[mt][tg][e] = (f32x4){0.f, 0.f, 0.f, 0.f};
#pragma unroll
    for (int ks = 0; ks < 4; ks++) {
#pragma unroll
      for (int tg = 0; tg < 2; tg++) {
#pragma unroll
        for (int e = 0; e < 4; e++) {
          int nrow = tg * 64 + 4 * lr + e;
          int gp = (ks * 4 + quad + (nrow & 15)) & 15;
          bf16x8 b = *(const bf16x8*)(&Wlds[nrow * 128 + gp * 8]);
          acc[0][tg][e] = __builtin_amdgcn_mfma_f32_16x16x32_bf16(a[0][ks], b, acc[0][tg][e], 0, 0, 0);
          acc[1][tg][e] = __builtin_amdgcn_mfma_f32_16x16x32_bf16(a[1][ks], b, acc[1][tg][e], 0, 0, 0);
        }
      }
    }
    u16* O = Os[mat];
#pragma unroll
    for (int mt = 0; mt < 2; mt++) {
      int row0 = blockIdx.x * 128 + wave * 32 + mt * 16 + quad * 4;
#pragma unroll
      for (int tg = 0; tg < 2; tg++) {
        int c0 = tg * 64 + 4 * lr;
        float bg0 = 0.f, bg1 = 0.f, bg2 = 0.f, bg3 = 0.f;
        if (mat == 3) { bg0 = bg[c0]; bg1 = bg[c0+1]; bg2 = bg[c0+2]; bg3 = bg[c0+3]; }
#pragma unroll
        for (int reg = 0; reg < 4; reg++) {
          float v0 = acc[mt][tg][0][reg], v1 = acc[mt][tg][1][reg];
          float v2 = acc[mt][tg][2][reg], v3 = acc[mt][tg][3][reg];
          if (mat == 0) { v0 *= QK_SCALE; v1 *= QK_SCALE; v2 *= QK_SCALE; v3 *= QK_SCALE; }
          if (mat == 3) {
            v0 = 1.0f / (1.0f + __expf(-(v0 + bg0)));
            v1 = 1.0f / (1.0f + __expf(-(v1 + bg1)));
            v2 = 1.0f / (1.0f + __expf(-(v2 + bg2)));
            v3 = 1.0f / (1.0f + __expf(-(v3 + bg3)));
          }
          uint2 pk;
          pk.x = (unsigned)f2b(v0) | ((unsigned)f2b(v1) << 16);
          pk.y = (unsigned)f2b(v2) | ((unsigned)f2b(v3) << 16);
          *(uint2*)(O + (size_t)(row0 + reg) * D + c0) = pk;
        }
      }
    }
    __syncthreads();
  }
}

// ---------------- Kernel 2: attention per (r, h) ---- (unchanged) ------------
#define KSTRIDE 40
#define VSTRIDE 264
#define PSTRIDE 264
__global__ __launch_bounds__(256) void attn_kernel(
    const u16* __restrict__ q, const u16* __restrict__ k, const u16* __restrict__ v,
    const u16* __restrict__ g, const float* __restrict__ nb, const float* __restrict__ mask,
    u16* __restrict__ og)
{
  __shared__ __align__(16) u16 Kt[256 * KSTRIDE];
  __shared__ __align__(16) u16 Vt[32 * VSTRIDE];
  __shared__ __align__(16) u16 P[4 * 16 * PSTRIDE];
  int h = blockIdx.x & 3, r = blockIdx.x >> 2;
  int tid = threadIdx.x;
  {
    const u16* krow = k + ((size_t)r * N + tid) * D + h * KD;
#pragma unroll
    for (int ii = 0; ii < 4; ii++)
      *(bf16x8*)(&Kt[tid * KSTRIDE + ii * 8]) = *(const bf16x8*)(krow + ii * 8);
    const u16* vrow = v + ((size_t)r * N + tid) * D + h * KD;
#pragma unroll
    for (int c = 0; c < KD; c++)
      Vt[c * VSTRIDE + tid] = vrow[c];
  }
  __syncthreads();
  int wave = tid >> 6, lane = tid & 63;
  int lr = lane & 15, quad = lane >> 4;
  u16* Pw = &P[wave * 16 * PSTRIDE];

  for (int pass = 0; pass < 4; pass++) {
    int i0 = pass * 64 + wave * 16;
    bf16x8 af = *(const bf16x8*)(q + ((size_t)r * N + i0 + lr) * D + h * KD + quad * 8);
    f32x4 S[16];
#pragma unroll
    for (int t = 0; t < 16; t++) {
      bf16x8 bfr = *(const bf16x8*)(&Kt[(t * 16 + lr) * KSTRIDE + quad * 8]);
      S[t] = __builtin_amdgcn_mfma_f32_16x16x32_bf16(af, bfr, (f32x4){0.f,0.f,0.f,0.f}, 0, 0, 0);
    }
    float mx[4] = {-3e38f, -3e38f, -3e38f, -3e38f};
#pragma unroll
    for (int t = 0; t < 16; t++) {
      int j = t * 16 + lr;
      float bias = HUGE_MASK * (mask[r * N + j] - 1.0f);
      const float* nbp = &nb[(size_t)h * NN + (size_t)(i0 + quad * 4) * N + j];
#pragma unroll
      for (int reg = 0; reg < 4; reg++) {
        float val = S[t][reg] + bias + nbp[(size_t)reg * N];
        S[t][reg] = val;
        mx[reg] = fmaxf(mx[reg], val);
      }
    }
#pragma unroll
    for (int reg = 0; reg < 4; reg++) {
#pragma unroll
      for (int off = 8; off; off >>= 1)
        mx[reg] = fmaxf(mx[reg], __shfl_xor(mx[reg], off, 16));
    }
    float lsum[4] = {0.f, 0.f, 0.f, 0.f};
#pragma unroll
    for (int t = 0; t < 16; t++) {
#pragma unroll
      for (int reg = 0; reg < 4; reg++) {
        float p = __expf(S[t][reg] - mx[reg]);
        S[t][reg] = p;
        lsum[reg] += p;
      }
    }
#pragma unroll
    for (int reg = 0; reg < 4; reg++) {
#pragma unroll
      for (int off = 8; off; off >>= 1)
        lsum[reg] += __shfl_xor(lsum[reg], off, 16);
    }
#pragma unroll
    for (int t = 0; t < 16; t++) {
#pragma unroll
      for (int reg = 0; reg < 4; reg++)
        Pw[(quad * 4 + reg) * PSTRIDE + t * 16 + lr] = f2b(S[t][reg]);
    }
    __syncthreads();
    f32x4 o[2] = {(f32x4){0.f,0.f,0.f,0.f}, (f32x4){0.f,0.f,0.f,0.f}};
#pragma unroll
    for (int ks = 0; ks < 8; ks++) {
      bf16x8 pa = *(const bf16x8*)(&Pw[lr * PSTRIDE + ks * 32 + quad * 8]);
#pragma unroll
      for (int u = 0; u < 2; u++) {
        bf16x8 vb = *(const bf16x8*)(&Vt[(u * 16 + lr) * VSTRIDE + ks * 32 + quad * 8]);
        o[u] = __builtin_amdgcn_mfma_f32_16x16x32_bf16(pa, vb, o[u], 0, 0, 0);
      }
    }
#pragma unroll
    for (int u = 0; u < 2; u++) {
#pragma unroll
      for (int reg = 0; reg < 4; reg++) {
        int i = i0 + quad * 4 + reg;
        int c = h * KD + u * 16 + lr;
        size_t idx = ((size_t)r * N + i) * D + c;
        float val = o[u][reg] / lsum[reg] * b2f(g[idx]);
        og[idx] = f2b(val);
      }
    }
  }
}

// ---------------- Kernel 3: output projection (LDS-staged wo) ---------------
__global__ __launch_bounds__(256) void out_kernel(
    const u16* __restrict__ og, const float* __restrict__ wo, const float* __restrict__ bo,
    const float* __restrict__ mask, float* __restrict__ out)
{
  __shared__ __align__(16) u16 Wlds[128 * 128];
  int tid = threadIdx.x;
  stage_w(wo, Wlds, tid);
  int wave = tid >> 6, lane = tid & 63;
  int lr = lane & 15, quad = lane >> 4;
  bf16x8 a[2][4];
#pragma unroll
  for (int mt = 0; mt < 2; mt++) {
    int arow = blockIdx.x * 128 + wave * 32 + mt * 16 + lr;
#pragma unroll
    for (int ks = 0; ks < 4; ks++)
      a[mt][ks] = *(const bf16x8*)(og + (size_t)arow * D + ks * 32 + quad * 8);
  }
  __syncthreads();
  f32x4 acc[2][2][4];
#pragma unroll
  for (int mt = 0; mt < 2; mt++)
#pragma unroll
    for (int tg = 0; tg < 2; tg++)
#pragma unroll
      for (int e = 0; e < 4; e++) acc[mt][tg][e] = (f32x4){0.f, 0.f, 0.f, 0.f};
#pragma unroll
  for (int ks = 0; ks < 4; ks++) {
#pragma unroll
    for (int tg = 0; tg < 2; tg++) {
#pragma unroll
      for (int e = 0; e < 4; e++) {
        int nrow = tg * 64 + 4 * lr + e;
        int gp = (ks * 4 + quad + (nrow & 15)) & 15;
        bf16x8 b = *(const bf16x8*)(&Wlds[nrow * 128 + gp * 8]);
        acc[0][tg][e] = __builtin_amdgcn_mfma_f32_16x16x32_bf16(a[0][ks], b, acc[0][tg][e], 0, 0, 0);
        acc[1][tg][e] = __builtin_amdgcn_mfma_f32_16x16x32_bf16(a[1][ks], b, acc[1][tg][e], 0, 0, 0);
      }
    }
  }
#pragma unroll
  for (int mt = 0; mt < 2; mt++) {
    int row0 = blockIdx.x * 128 + wave * 32 + mt * 16 + quad * 4;
#pragma unroll
    for (int tg = 0; tg < 2; tg++) {
      int c0 = tg * 64 + 4 * lr;
      float4 bo4 = *(const float4*)(bo + c0);
#pragma unroll
      for (int reg = 0; reg < 4; reg++) {
        int pos = row0 + reg;
        float m = mask[pos];
        float4 o4;
        o4.x = (acc[mt][tg][0][reg] + bo4.x) * m;
        o4.y = (acc[mt][tg][1][reg] + bo4.y) * m;
        o4.z = (acc[mt][tg][2][reg] + bo4.z) * m;
        o4.w = (acc[mt][tg][3][reg] + bo4.w) * m;
        *(float4*)(out + (size_t)pos * D + c0) = o4;
      }
    }
  }
}

extern "C" void kernel_launch(void* const* d_in, const int* in_sizes, int n_in,
                              void* d_out, int out_size, void* d_ws, size_t ws_size,
                              hipStream_t stream)
{
  const float* pa   = (const float*)d_in[0];
  const float* mask = (const float*)d_in[1];
  const float* lns  = (const float*)d_in[2];
  const float* lnb  = (const float*)d_in[3];
  const float* w2d  = (const float*)d_in[4];
  const float* wq   = (const float*)d_in[5];
  const float* wk   = (const float*)d_in[6];
  const float* wv   = (const float*)d_in[7];
  const float* wg   = (const float*)d_in[8];
  const float* bg   = (const float*)d_in[9];
  const float* wo   = (const float*)d_in[10];
  const float* bo   = (const float*)d_in[11];

  const size_t ARR = (size_t)NN * D;     // 8M elements
  u16* q  = (u16*)d_ws;
  u16* k  = q + ARR;
  u16* v  = k + ARR;
  u16* g  = v + ARR;
  u16* og = g + ARR;
  float* nb = (float*)(og + ARR);        // NH*NN floats = 1 MB

  projln_kernel<<<512, 256, 0, stream>>>(pa, lns, lnb, w2d, wq, wk, wv, wg, bg, q, k, v, g, nb);
  attn_kernel<<<N * NH, 256, 0, stream>>>(q, k, v, g, nb, mask, og);
  out_kernel<<<512, 256, 0, stream>>>(og, wo, bo, mask, (float*)d_out);
}

// Round 5
// 202.279 us; speedup vs baseline: 1.3851x; 1.0738x over previous
//
#include <hip/hip_runtime.h>
#include <hip/hip_bf16.h>

typedef unsigned short u16;
typedef __attribute__((ext_vector_type(8))) short bf16x8;
typedef __attribute__((ext_vector_type(4))) float f32x4;

#define N 256
#define D 128
#define NH 4
#define KD 32
#define NN 65536
#define QK_SCALE 0.17677669529663687f
#define HUGE_MASK 32768.0f

__device__ __forceinline__ float b2f(u16 s) {
  union { float f; unsigned u; } x; x.u = ((unsigned)s) << 16; return x.f;
}
__device__ __forceinline__ u16 f2b(float f) {
  union { float f; unsigned u; } x; x.f = f;
  unsigned r = x.u + 0x7fff + ((x.u >> 16) & 1);
  return (u16)(r >> 16);
}

// Stage a 128x128 fp32 weight matrix into LDS as bf16 with XOR-rotate swizzle:
// 8-elem group g of row n lands at group gp = (g + (n&15)) & 15.
__device__ __forceinline__ void stage_w(const float* __restrict__ W, u16* Wlds, int tid) {
  int row = tid >> 1, cb = (tid & 1) * 64;
#pragma unroll
  for (int j = 0; j < 8; j++) {
    float4 f0 = *(const float4*)(W + row * 128 + cb + j * 8);
    float4 f1 = *(const float4*)(W + row * 128 + cb + j * 8 + 4);
    uint4 pk;
    pk.x = (unsigned)f2b(f0.x) | ((unsigned)f2b(f0.y) << 16);
    pk.y = (unsigned)f2b(f0.z) | ((unsigned)f2b(f0.w) << 16);
    pk.z = (unsigned)f2b(f1.x) | ((unsigned)f2b(f1.y) << 16);
    pk.w = (unsigned)f2b(f1.z) | ((unsigned)f2b(f1.w) << 16);
    int g = (cb >> 3) + j;
    int gp = (g + (row & 15)) & 15;
    *(uint4*)(&Wlds[row * 128 + gp * 8]) = pk;
  }
}

// ---------------- Kernel 1: fused LN + nb + q,k,v,g projections --------------
// nb is written TRANSPOSED: nbT[h][j][i] (fp32) so attn can float4-load along i.
__global__ __launch_bounds__(256) void projln_kernel(
    const float* __restrict__ pa, const float* __restrict__ lns, const float* __restrict__ lnb,
    const float* __restrict__ w2d,
    const float* __restrict__ wq, const float* __restrict__ wk,
    const float* __restrict__ wv, const float* __restrict__ wg,
    const float* __restrict__ bg,
    u16* __restrict__ q, u16* __restrict__ k, u16* __restrict__ v, u16* __restrict__ g,
    float* __restrict__ nbT)
{
  __shared__ __align__(16) u16 Wlds[128 * 128];
  int tid = threadIdx.x;
  int wave = tid >> 6, lane = tid & 63;
  int lr = lane & 15, quad = lane >> 4;

  bf16x8 a[2][4];
#pragma unroll
  for (int mt = 0; mt < 2; mt++) {
    int row = blockIdx.x * 128 + wave * 32 + mt * 16 + lr;
    const float* rp = pa + (size_t)row * D;
    float xv[4][8];
    float s = 0.f, ss = 0.f;
#pragma unroll
    for (int ks = 0; ks < 4; ks++) {
      float4 a0 = *(const float4*)(rp + ks * 32 + quad * 8);
      float4 a1 = *(const float4*)(rp + ks * 32 + quad * 8 + 4);
      xv[ks][0] = a0.x; xv[ks][1] = a0.y; xv[ks][2] = a0.z; xv[ks][3] = a0.w;
      xv[ks][4] = a1.x; xv[ks][5] = a1.y; xv[ks][6] = a1.z; xv[ks][7] = a1.w;
#pragma unroll
      for (int j = 0; j < 8; j++) { s += xv[ks][j]; ss += xv[ks][j] * xv[ks][j]; }
    }
    s  += __shfl_xor(s, 16, 64);  ss += __shfl_xor(ss, 16, 64);
    s  += __shfl_xor(s, 32, 64);  ss += __shfl_xor(ss, 32, 64);
    float mu = s * (1.0f / D);
    float var = ss * (1.0f / D) - mu * mu;
    float rs = rsqrtf(var + 1e-5f);
#pragma unroll
    for (int ks = 0; ks < 4; ks++) {
      float4 s0 = *(const float4*)(lns + ks * 32 + quad * 8);
      float4 s1 = *(const float4*)(lns + ks * 32 + quad * 8 + 4);
      float4 b0 = *(const float4*)(lnb + ks * 32 + quad * 8);
      float4 b1 = *(const float4*)(lnb + ks * 32 + quad * 8 + 4);
      float sc[8] = {s0.x,s0.y,s0.z,s0.w,s1.x,s1.y,s1.z,s1.w};
      float bi[8] = {b0.x,b0.y,b0.z,b0.w,b1.x,b1.y,b1.z,b1.w};
#pragma unroll
      for (int j = 0; j < 8; j++) xv[ks][j] = (xv[ks][j] - mu) * rs * sc[j] + bi[j];
    }
#pragma unroll
    for (int h = 0; h < NH; h++) {
      float p = 0.f;
#pragma unroll
      for (int ks = 0; ks < 4; ks++) {
        float4 w0 = *(const float4*)(w2d + h * D + ks * 32 + quad * 8);
        float4 w1 = *(const float4*)(w2d + h * D + ks * 32 + quad * 8 + 4);
        p += xv[ks][0]*w0.x + xv[ks][1]*w0.y + xv[ks][2]*w0.z + xv[ks][3]*w0.w
           + xv[ks][4]*w1.x + xv[ks][5]*w1.y + xv[ks][6]*w1.z + xv[ks][7]*w1.w;
      }
      p += __shfl_xor(p, 16, 64);
      p += __shfl_xor(p, 32, 64);
      if (quad == 0)
        nbT[(size_t)h * NN + (size_t)(row & 255) * 256 + (row >> 8)] = p;
    }
#pragma unroll
    for (int ks = 0; ks < 4; ks++)
#pragma unroll
      for (int j = 0; j < 8; j++) a[mt][ks][j] = (short)f2b(xv[ks][j]);
  }

  const float* Ws[4] = {wq, wk, wv, wg};
  u16* Os[4] = {q, k, v, g};
#pragma unroll
  for (int mat = 0; mat < 4; mat++) {
    stage_w(Ws[mat], Wlds, tid);
    __syncthreads();
    f32x4 acc[2][2][4];
#pragma unroll
    for (int mt = 0; mt < 2; mt++)
#pragma unroll
      for (int tg = 0; tg < 2; tg++)
#pragma unroll
        for (int e = 0; e < 4; e++) acc[mt][tg][e] = (f32x4){0.f, 0.f, 0.f, 0.f};
#pragma unroll
    for (int ks = 0; ks < 4; ks++) {
#pragma unroll
      for (int tg = 0; tg < 2; tg++) {
#pragma unroll
        for (int e = 0; e < 4; e++) {
          int nrow = tg * 64 + 4 * lr + e;
          int gp = (ks * 4 + quad + (nrow & 15)) & 15;
          bf16x8 b = *(const bf16x8*)(&Wlds[nrow * 128 + gp * 8]);
          acc[0][tg][e] = __builtin_amdgcn_mfma_f32_16x16x32_bf16(a[0][ks], b, acc[0][tg][e], 0, 0, 0);
          acc[1][tg][e] = __builtin_amdgcn_mfma_f32_16x16x32_bf16(a[1][ks], b, acc[1][tg][e], 0, 0, 0);
        }
      }
    }
    u16* O = Os[mat];
#pragma unroll
    for (int mt = 0; mt < 2; mt++) {
      int row0 = blockIdx.x * 128 + wave * 32 + mt * 16 + quad * 4;
#pragma unroll
      for (int tg = 0; tg < 2; tg++) {
        int c0 = tg * 64 + 4 * lr;
        float bg0 = 0.f, bg1 = 0.f, bg2 = 0.f, bg3 = 0.f;
        if (mat == 3) { bg0 = bg[c0]; bg1 = bg[c0+1]; bg2 = bg[c0+2]; bg3 = bg[c0+3]; }
#pragma unroll
        for (int reg = 0; reg < 4; reg++) {
          float v0 = acc[mt][tg][0][reg], v1 = acc[mt][tg][1][reg];
          float v2 = acc[mt][tg][2][reg], v3 = acc[mt][tg][3][reg];
          if (mat == 0) { v0 *= QK_SCALE; v1 *= QK_SCALE; v2 *= QK_SCALE; v3 *= QK_SCALE; }
          if (mat == 3) {
            v0 = 1.0f / (1.0f + __expf(-(v0 + bg0)));
            v1 = 1.0f / (1.0f + __expf(-(v1 + bg1)));
            v2 = 1.0f / (1.0f + __expf(-(v2 + bg2)));
            v3 = 1.0f / (1.0f + __expf(-(v3 + bg3)));
          }
          uint2 pk;
          pk.x = (unsigned)f2b(v0) | ((unsigned)f2b(v1) << 16);
          pk.y = (unsigned)f2b(v2) | ((unsigned)f2b(v3) << 16);
          *(uint2*)(O + (size_t)(row0 + reg) * D + c0) = pk;
        }
      }
    }
    __syncthreads();
  }
}

// ---------------- Kernel 2: attention per (r, h) — fragment-ordered LDS ------
// Kf: chunk (t*4+quad)*16+lr   = K[t*16+lr][quad*8..+7]          (16 KB)
// Vf: chunk ((ks*2+e)*4+q)*16+lr = V[ks*32+q*8..+7][2*lr+e]      (16 KB)
// Pf: per-wave, chunk (ks*4+q)*16+lr = P[lr][ks*32+q*8..+7]      (8 KB x 4)
// All MFMA-frag LDS accesses are lane-sequential 16 B -> conflict-free.
__global__ __launch_bounds__(256) void attn_kernel(
    const u16* __restrict__ q, const u16* __restrict__ k, const u16* __restrict__ v,
    const u16* __restrict__ g, const float* __restrict__ nbT, const float* __restrict__ mask,
    u16* __restrict__ og)
{
  __shared__ __align__(16) u16 Kf[8192];
  __shared__ __align__(16) u16 Vf[8192];
  __shared__ __align__(16) u16 Pf[16384];
  __shared__ float bias_lds[256];
  int h = blockIdx.x & 3, r = blockIdx.x >> 2;
  int tid = threadIdx.x;
  {
    int j = tid;
    const u16* krow = k + ((size_t)r * N + j) * D + h * KD;
    int t = j >> 4, lrj = j & 15;
#pragma unroll
    for (int qc = 0; qc < 4; qc++)
      *(bf16x8*)(&Kf[((t * 4 + qc) * 16 + lrj) * 8]) = *(const bf16x8*)(krow + qc * 8);
    const u16* vrow = v + ((size_t)r * N + j) * D + h * KD;
    int ks = j >> 5, qj = (j >> 3) & 3, jj = j & 7;
#pragma unroll
    for (int c = 0; c < 32; c++)
      Vf[(((ks * 2 + (c & 1)) * 4 + qj) * 16 + (c >> 1)) * 8 + jj] = vrow[c];
    bias_lds[tid] = HUGE_MASK * (mask[r * N + tid] - 1.0f);
  }
  __syncthreads();
  int wave = tid >> 6, lane = tid & 63;
  int lr = lane & 15, quad = lane >> 4;
  u16* Pw = &Pf[wave * 4096];
  float bias_v[16];
#pragma unroll
  for (int t = 0; t < 16; t++) bias_v[t] = bias_lds[t * 16 + lr];
  const float* nbh = nbT + (size_t)h * NN;

  for (int pass = 0; pass < 4; pass++) {
    int i0 = pass * 64 + wave * 16;
    bf16x8 af = *(const bf16x8*)(q + ((size_t)r * N + i0 + lr) * D + h * KD + quad * 8);
    f32x4 S[16];
#pragma unroll
    for (int t = 0; t < 16; t++) {
      bf16x8 bfr = *(const bf16x8*)(&Kf[((t * 4 + quad) * 16 + lr) * 8]);
      S[t] = __builtin_amdgcn_mfma_f32_16x16x32_bf16(af, bfr, (f32x4){0.f,0.f,0.f,0.f}, 0, 0, 0);
    }
    float mx[4] = {-3e38f, -3e38f, -3e38f, -3e38f};
#pragma unroll
    for (int t = 0; t < 16; t++) {
      float4 nb4 = *(const float4*)(nbh + (size_t)(t * 16 + lr) * N + i0 + quad * 4);
      float bl = bias_v[t];
      S[t][0] += nb4.x + bl;  S[t][1] += nb4.y + bl;
      S[t][2] += nb4.z + bl;  S[t][3] += nb4.w + bl;
      mx[0] = fmaxf(mx[0], S[t][0]); mx[1] = fmaxf(mx[1], S[t][1]);
      mx[2] = fmaxf(mx[2], S[t][2]); mx[3] = fmaxf(mx[3], S[t][3]);
    }
#pragma unroll
    for (int reg = 0; reg < 4; reg++) {
#pragma unroll
      for (int off = 8; off; off >>= 1)
        mx[reg] = fmaxf(mx[reg], __shfl_xor(mx[reg], off, 16));
    }
    float lsum[4] = {0.f, 0.f, 0.f, 0.f};
#pragma unroll
    for (int t = 0; t < 16; t++) {
      int j = t * 16 + lr;
      int cbase = ((j >> 5) * 4 + ((j >> 3) & 3)) * 128 + (j & 7);
#pragma unroll
      for (int reg = 0; reg < 4; reg++) {
        float p = __expf(S[t][reg] - mx[reg]);
        lsum[reg] += p;
        union { float f; unsigned u; } cv; cv.f = p;
        Pw[cbase + (quad * 4 + reg) * 8] = (u16)((cv.u + 0x8000u) >> 16);
      }
    }
#pragma unroll
    for (int reg = 0; reg < 4; reg++) {
#pragma unroll
      for (int off = 8; off; off >>= 1)
        lsum[reg] += __shfl_xor(lsum[reg], off, 16);
    }
    __asm__ __volatile__("s_waitcnt lgkmcnt(0)" ::: "memory");
    f32x4 o[2] = {(f32x4){0.f,0.f,0.f,0.f}, (f32x4){0.f,0.f,0.f,0.f}};
#pragma unroll
    for (int ks = 0; ks < 8; ks++) {
      bf16x8 pa = *(const bf16x8*)(&Pw[((ks * 4 + quad) * 16 + lr) * 8]);
#pragma unroll
      for (int e = 0; e < 2; e++) {
        bf16x8 vb = *(const bf16x8*)(&Vf[(((ks * 2 + e) * 4 + quad) * 16 + lr) * 8]);
        o[e] = __builtin_amdgcn_mfma_f32_16x16x32_bf16(pa, vb, o[e], 0, 0, 0);
      }
    }
#pragma unroll
    for (int reg = 0; reg < 4; reg++) {
      float inv = __builtin_amdgcn_rcpf(lsum[reg]);
      int i = i0 + quad * 4 + reg;
      size_t base = ((size_t)r * N + i) * D + h * KD + 2 * lr;
      unsigned gv = *(const unsigned*)(g + base);
      float r0 = o[0][reg] * inv * b2f((u16)(gv & 0xffff));
      float r1 = o[1][reg] * inv * b2f((u16)(gv >> 16));
      *(unsigned*)(og + base) = (unsigned)f2b(r0) | ((unsigned)f2b(r1) << 16);
    }
  }
}

// ---------------- Kernel 3: output projection (LDS-staged wo) ---------------
__global__ __launch_bounds__(256) void out_kernel(
    const u16* __restrict__ og, const float* __restrict__ wo, const float* __restrict__ bo,
    const float* __restrict__ mask, float* __restrict__ out)
{
  __shared__ __align__(16) u16 Wlds[128 * 128];
  int tid = threadIdx.x;
  stage_w(wo, Wlds, tid);
  int wave = tid >> 6, lane = tid & 63;
  int lr = lane & 15, quad = lane >> 4;
  bf16x8 a[2][4];
#pragma unroll
  for (int mt = 0; mt < 2; mt++) {
    int arow = blockIdx.x * 128 + wave * 32 + mt * 16 + lr;
#pragma unroll
    for (int ks = 0; ks < 4; ks++)
      a[mt][ks] = *(const bf16x8*)(og + (size_t)arow * D + ks * 32 + quad * 8);
  }
  __syncthreads();
  f32x4 acc[2][2][4];
#pragma unroll
  for (int mt = 0; mt < 2; mt++)
#pragma unroll
    for (int tg = 0; tg < 2; tg++)
#pragma unroll
      for (int e = 0; e < 4; e++) acc[mt][tg][e] = (f32x4){0.f, 0.f, 0.f, 0.f};
#pragma unroll
  for (int ks = 0; ks < 4; ks++) {
#pragma unroll
    for (int tg = 0; tg < 2; tg++) {
#pragma unroll
      for (int e = 0; e < 4; e++) {
        int nrow = tg * 64 + 4 * lr + e;
        int gp = (ks * 4 + quad + (nrow & 15)) & 15;
        bf16x8 b = *(const bf16x8*)(&Wlds[nrow * 128 + gp * 8]);
        acc[0][tg][e] = __builtin_amdgcn_mfma_f32_16x16x32_bf16(a[0][ks], b, acc[0][tg][e], 0, 0, 0);
        acc[1][tg][e] = __builtin_amdgcn_mfma_f32_16x16x32_bf16(a[1][ks], b, acc[1][tg][e], 0, 0, 0);
      }
    }
  }
#pragma unroll
  for (int mt = 0; mt < 2; mt++) {
    int row0 = blockIdx.x * 128 + wave * 32 + mt * 16 + quad * 4;
#pragma unroll
    for (int tg = 0; tg < 2; tg++) {
      int c0 = tg * 64 + 4 * lr;
      float4 bo4 = *(const float4*)(bo + c0);
#pragma unroll
      for (int reg = 0; reg < 4; reg++) {
        int pos = row0 + reg;
        float m = mask[pos];
        float4 o4;
        o4.x = (acc[mt][tg][0][reg] + bo4.x) * m;
        o4.y = (acc[mt][tg][1][reg] + bo4.y) * m;
        o4.z = (acc[mt][tg][2][reg] + bo4.z) * m;
        o4.w = (acc[mt][tg][3][reg] + bo4.w) * m;
        *(float4*)(out + (size_t)pos * D + c0) = o4;
      }
    }
  }
}

extern "C" void kernel_launch(void* const* d_in, const int* in_sizes, int n_in,
                              void* d_out, int out_size, void* d_ws, size_t ws_size,
                              hipStream_t stream)
{
  const float* pa   = (const float*)d_in[0];
  const float* mask = (const float*)d_in[1];
  const float* lns  = (const float*)d_in[2];
  const float* lnb  = (const float*)d_in[3];
  const float* w2d  = (const float*)d_in[4];
  const float* wq   = (const float*)d_in[5];
  const float* wk   = (const float*)d_in[6];
  const float* wv   = (const float*)d_in[7];
  const float* wg   = (const float*)d_in[8];
  const float* bg   = (const float*)d_in[9];
  const float* wo   = (const float*)d_in[10];
  const float* bo   = (const float*)d_in[11];

  const size_t ARR = (size_t)NN * D;     // 8M elements
  u16* q  = (u16*)d_ws;
  u16* k  = q + ARR;
  u16* v  = k + ARR;
  u16* g  = v + ARR;
  u16* og = g + ARR;
  float* nbT = (float*)(og + ARR);       // NH*NN floats, TRANSPOSED [h][j][i]

  projln_kernel<<<512, 256, 0, stream>>>(pa, lns, lnb, w2d, wq, wk, wv, wg, bg, q, k, v, g, nbT);
  attn_kernel<<<N * NH, 256, 0, stream>>>(q, k, v, g, nbT, mask, og);
  out_kernel<<<512, 256, 0, stream>>>(og, wo, bo, mask, (float*)d_out);
}

// Round 6
// 187.612 us; speedup vs baseline: 1.4934x; 1.0782x over previous
//
#include <hip/hip_runtime.h>
#include <hip/hip_bf16.h>

typedef unsigned short u16;
typedef __attribute__((ext_vector_type(8))) short bf16x8;
typedef __attribute__((ext_vector_type(4))) float f32x4;
typedef __attribute__((address_space(3))) unsigned lds_u32;
typedef const __attribute__((address_space(1))) unsigned glb_u32;

#define N 256
#define D 128
#define NH 4
#define KD 32
#define NN 65536
#define QK_SCALE 0.17677669529663687f
#define HUGE_MASK 32768.0f

__device__ __forceinline__ float b2f(u16 s) {
  union { float f; unsigned u; } x; x.u = ((unsigned)s) << 16; return x.f;
}
__device__ __forceinline__ u16 f2b(float f) {
  union { float f; unsigned u; } x; x.f = f;
  unsigned r = x.u + 0x7fff + ((x.u >> 16) & 1);
  return (u16)(r >> 16);
}

// ---- Kernel 0: convert 5 weight mats fp32 -> bf16 into the swizzled LDS
// image layout: wb[mat][row*128 + gp*8 + j] = bf16(W[row][g*8+j]),
// gp = (g + (row&15)) & 15. One 8-elem group per thread.
__global__ __launch_bounds__(256) void prep_w_kernel(
    const float* __restrict__ wq, const float* __restrict__ wk,
    const float* __restrict__ wv, const float* __restrict__ wg,
    const float* __restrict__ wo, u16* __restrict__ wb)
{
  int idx = blockIdx.x * 256 + threadIdx.x;          // 0 .. 10239
  const float* srcs[5] = {wq, wk, wv, wg, wo};
  int mat = idx >> 11, rem = idx & 2047;
  int row = rem >> 4, g = rem & 15;
  int gp = (g + (row & 15)) & 15;
  const float* s = srcs[mat] + row * 128 + g * 8;
  float4 f0 = *(const float4*)(s);
  float4 f1 = *(const float4*)(s + 4);
  uint4 pk;
  pk.x = (unsigned)f2b(f0.x) | ((unsigned)f2b(f0.y) << 16);
  pk.y = (unsigned)f2b(f0.z) | ((unsigned)f2b(f0.w) << 16);
  pk.z = (unsigned)f2b(f1.x) | ((unsigned)f2b(f1.y) << 16);
  pk.w = (unsigned)f2b(f1.z) | ((unsigned)f2b(f1.w) << 16);
  *(uint4*)(wb + (size_t)mat * 16384 + row * 128 + gp * 8) = pk;
}

// Async-stage 32 KB (one swizzled weight mat) global -> LDS, width 16.
// LDS dest is wave-uniform base + lane*16 (HW rule), so copy is linear.
__device__ __forceinline__ void async_stage(const u16* __restrict__ gsrc, u16* lds, int tid) {
  int lane = tid & 63, wave = tid >> 6;
  u16* lbase = lds + wave * 512;                 // 1 KB per wave per pass
  const u16* gbase = gsrc + wave * 512 + lane * 8;
#pragma unroll
  for (int p = 0; p < 8; p++) {
    __builtin_amdgcn_global_load_lds((glb_u32*)(gbase + p * 2048),
                                     (lds_u32*)(lbase + p * 2048), 16, 0, 0);
  }
}

// ---------------- Kernel 1: fused LN + nb + q,k,v,g projections --------------
// Grid 512 x 256thr. M=128 rows/block, 2 m-tiles/wave. Weights double-buffered
// via global_load_lds from pre-swizzled wb. nbT[h][j][i] fp32.
__global__ __launch_bounds__(256) void projln_kernel(
    const float* __restrict__ pa, const float* __restrict__ lns, const float* __restrict__ lnb,
    const float* __restrict__ w2d, const u16* __restrict__ wb, const float* __restrict__ bg,
    u16* __restrict__ q, u16* __restrict__ k, u16* __restrict__ v, u16* __restrict__ g,
    float* __restrict__ nbT)
{
  __shared__ __align__(16) u16 Wl[2][16384];
  int tid = threadIdx.x;
  int wave = tid >> 6, lane = tid & 63;
  int lr = lane & 15, quad = lane >> 4;

  async_stage(wb, Wl[0], tid);   // mat 0 in flight while LN runs

  bf16x8 a[2][4];
#pragma unroll
  for (int mt = 0; mt < 2; mt++) {
    int row = blockIdx.x * 128 + wave * 32 + mt * 16 + lr;
    const float* rp = pa + (size_t)row * D;
    float xv[4][8];
    float s = 0.f, ss = 0.f;
#pragma unroll
    for (int ks = 0; ks < 4; ks++) {
      float4 a0 = *(const float4*)(rp + ks * 32 + quad * 8);
      float4 a1 = *(const float4*)(rp + ks * 32 + quad * 8 + 4);
      xv[ks][0] = a0.x; xv[ks][1] = a0.y; xv[ks][2] = a0.z; xv[ks][3] = a0.w;
      xv[ks][4] = a1.x; xv[ks][5] = a1.y; xv[ks][6] = a1.z; xv[ks][7] = a1.w;
#pragma unroll
      for (int j = 0; j < 8; j++) { s += xv[ks][j]; ss += xv[ks][j] * xv[ks][j]; }
    }
    s  += __shfl_xor(s, 16, 64);  ss += __shfl_xor(ss, 16, 64);
    s  += __shfl_xor(s, 32, 64);  ss += __shfl_xor(ss, 32, 64);
    float mu = s * (1.0f / D);
    float var = ss * (1.0f / D) - mu * mu;
    float rs = rsqrtf(var + 1e-5f);
#pragma unroll
    for (int ks = 0; ks < 4; ks++) {
      float4 s0 = *(const float4*)(lns + ks * 32 + quad * 8);
      float4 s1 = *(const float4*)(lns + ks * 32 + quad * 8 + 4);
      float4 b0 = *(const float4*)(lnb + ks * 32 + quad * 8);
      float4 b1 = *(const float4*)(lnb + ks * 32 + quad * 8 + 4);
      float sc[8] = {s0.x,s0.y,s0.z,s0.w,s1.x,s1.y,s1.z,s1.w};
      float bi[8] = {b0.x,b0.y,b0.z,b0.w,b1.x,b1.y,b1.z,b1.w};
#pragma unroll
      for (int j = 0; j < 8; j++) xv[ks][j] = (xv[ks][j] - mu) * rs * sc[j] + bi[j];
    }
#pragma unroll
    for (int h = 0; h < NH; h++) {
      float p = 0.f;
#pragma unroll
      for (int ks = 0; ks < 4; ks++) {
        float4 w0 = *(const float4*)(w2d + h * D + ks * 32 + quad * 8);
        float4 w1 = *(const float4*)(w2d + h * D + ks * 32 + quad * 8 + 4);
        p += xv[ks][0]*w0.x + xv[ks][1]*w0.y + xv[ks][2]*w0.z + xv[ks][3]*w0.w
           + xv[ks][4]*w1.x + xv[ks][5]*w1.y + xv[ks][6]*w1.z + xv[ks][7]*w1.w;
      }
      p += __shfl_xor(p, 16, 64);
      p += __shfl_xor(p, 32, 64);
      if (quad == 0)
        nbT[(size_t)h * NN + (size_t)(row & 255) * 256 + (row >> 8)] = p;
    }
#pragma unroll
    for (int ks = 0; ks < 4; ks++)
#pragma unroll
      for (int j = 0; j < 8; j++) a[mt][ks][j] = (short)f2b(xv[ks][j]);
  }
  __syncthreads();   // drains mat-0 global_load_lds (vmcnt) + all waves ready

  u16* Os[4] = {q, k, v, g};
#pragma unroll
  for (int mat = 0; mat < 4; mat++) {
    if (mat < 3) async_stage(wb + (size_t)(mat + 1) * 16384, Wl[(mat + 1) & 1], tid);
    const u16* Wcur = Wl[mat & 1];
    f32x4 acc[2][2][4];
#pragma unroll
    for (int mt = 0; mt < 2; mt++)
#pragma unroll
      for (int tg = 0; tg < 2; tg++)
#pragma unroll
        for (int e = 0; e < 4; e++) acc[mt][tg][e] = (f32x4){0.f, 0.f, 0.f, 0.f};
#pragma unroll
    for (int ks = 0; ks < 4; ks++) {
#pragma unroll
      for (int tg = 0; tg < 2; tg++) {
#pragma unroll
        for (int e = 0; e < 4; e++) {
          int nrow = tg * 64 + 4 * lr + e;
          int gp = (ks * 4 + quad + (nrow & 15)) & 15;
          bf16x8 b = *(const bf16x8*)(&Wcur[nrow * 128 + gp * 8]);
          acc[0][tg][e] = __builtin_amdgcn_mfma_f32_16x16x32_bf16(a[0][ks], b, acc[0][tg][e], 0, 0, 0);
          acc[1][tg][e] = __builtin_amdgcn_mfma_f32_16x16x32_bf16(a[1][ks], b, acc[1][tg][e], 0, 0, 0);
        }
      }
    }
    u16* O = Os[mat];
#pragma unroll
    for (int mt = 0; mt < 2; mt++) {
      int row0 = blockIdx.x * 128 + wave * 32 + mt * 16 + quad * 4;
#pragma unroll
      for (int tg = 0; tg < 2; tg++) {
        int c0 = tg * 64 + 4 * lr;
        float bg0 = 0.f, bg1 = 0.f, bg2 = 0.f, bg3 = 0.f;
        if (mat == 3) { bg0 = bg[c0]; bg1 = bg[c0+1]; bg2 = bg[c0+2]; bg3 = bg[c0+3]; }
#pragma unroll
        for (int reg = 0; reg < 4; reg++) {
          float v0 = acc[mt][tg][0][reg], v1 = acc[mt][tg][1][reg];
          float v2 = acc[mt][tg][2][reg], v3 = acc[mt][tg][3][reg];
          if (mat == 0) { v0 *= QK_SCALE; v1 *= QK_SCALE; v2 *= QK_SCALE; v3 *= QK_SCALE; }
          if (mat == 3) {
            v0 = 1.0f / (1.0f + __expf(-(v0 + bg0)));
            v1 = 1.0f / (1.0f + __expf(-(v1 + bg1)));
            v2 = 1.0f / (1.0f + __expf(-(v2 + bg2)));
            v3 = 1.0f / (1.0f + __expf(-(v3 + bg3)));
          }
          uint2 pk;
          pk.x = (unsigned)f2b(v0) | ((unsigned)f2b(v1) << 16);
          pk.y = (unsigned)f2b(v2) | ((unsigned)f2b(v3) << 16);
          *(uint2*)(O + (size_t)(row0 + reg) * D + c0) = pk;
        }
      }
    }
    __syncthreads();   // next buffer staged (vmcnt drained) + reads done
  }
}

// ---------------- Kernel 2: attention per (r, h) — fragment-ordered LDS ------
__global__ __launch_bounds__(256) void attn_kernel(
    const u16* __restrict__ q, const u16* __restrict__ k, const u16* __restrict__ v,
    const u16* __restrict__ g, const float* __restrict__ nbT, const float* __restrict__ mask,
    u16* __restrict__ og)
{
  __shared__ __align__(16) u16 Kf[8192];
  __shared__ __align__(16) u16 Vf[8192];
  __shared__ __align__(16) u16 Pf[16384];
  __shared__ float bias_lds[256];
  int h = blockIdx.x & 3, r = blockIdx.x >> 2;
  int tid = threadIdx.x;
  {
    int j = tid;
    const u16* krow = k + ((size_t)r * N + j) * D + h * KD;
    int t = j >> 4, lrj = j & 15;
#pragma unroll
    for (int qc = 0; qc < 4; qc++)
      *(bf16x8*)(&Kf[((t * 4 + qc) * 16 + lrj) * 8]) = *(const bf16x8*)(krow + qc * 8);
    const u16* vrow = v + ((size_t)r * N + j) * D + h * KD;
    int ks = j >> 5, qj = (j >> 3) & 3, jj = j & 7;
#pragma unroll
    for (int c = 0; c < 32; c++)
      Vf[(((ks * 2 + (c & 1)) * 4 + qj) * 16 + (c >> 1)) * 8 + jj] = vrow[c];
    bias_lds[tid] = HUGE_MASK * (mask[r * N + tid] - 1.0f);
  }
  __syncthreads();
  int wave = tid >> 6, lane = tid & 63;
  int lr = lane & 15, quad = lane >> 4;
  u16* Pw = &Pf[wave * 4096];
  float bias_v[16];
#pragma unroll
  for (int t = 0; t < 16; t++) bias_v[t] = bias_lds[t * 16 + lr];
  const float* nbh = nbT + (size_t)h * NN;

  for (int pass = 0; pass < 4; pass++) {
    int i0 = pass * 64 + wave * 16;
    bf16x8 af = *(const bf16x8*)(q + ((size_t)r * N + i0 + lr) * D + h * KD + quad * 8);
    f32x4 S[16];
#pragma unroll
    for (int t = 0; t < 16; t++) {
      bf16x8 bfr = *(const bf16x8*)(&Kf[((t * 4 + quad) * 16 + lr) * 8]);
      S[t] = __builtin_amdgcn_mfma_f32_16x16x32_bf16(af, bfr, (f32x4){0.f,0.f,0.f,0.f}, 0, 0, 0);
    }
    float mx[4] = {-3e38f, -3e38f, -3e38f, -3e38f};
#pragma unroll
    for (int t = 0; t < 16; t++) {
      float4 nb4 = *(const float4*)(nbh + (size_t)(t * 16 + lr) * N + i0 + quad * 4);
      float bl = bias_v[t];
      S[t][0] += nb4.x + bl;  S[t][1] += nb4.y + bl;
      S[t][2] += nb4.z + bl;  S[t][3] += nb4.w + bl;
      mx[0] = fmaxf(mx[0], S[t][0]); mx[1] = fmaxf(mx[1], S[t][1]);
      mx[2] = fmaxf(mx[2], S[t][2]); mx[3] = fmaxf(mx[3], S[t][3]);
    }
#pragma unroll
    for (int reg = 0; reg < 4; reg++) {
#pragma unroll
      for (int off = 8; off; off >>= 1)
        mx[reg] = fmaxf(mx[reg], __shfl_xor(mx[reg], off, 16));
    }
    float lsum[4] = {0.f, 0.f, 0.f, 0.f};
#pragma unroll
    for (int t = 0; t < 16; t++) {
      int j = t * 16 + lr;
      int cbase = ((j >> 5) * 4 + ((j >> 3) & 3)) * 128 + (j & 7);
#pragma unroll
      for (int reg = 0; reg < 4; reg++) {
        float p = __expf(S[t][reg] - mx[reg]);
        lsum[reg] += p;
        union { float f; unsigned u; } cv; cv.f = p;
        Pw[cbase + (quad * 4 + reg) * 8] = (u16)((cv.u + 0x8000u) >> 16);
      }
    }
#pragma unroll
    for (int reg = 0; reg < 4; reg++) {
#pragma unroll
      for (int off = 8; off; off >>= 1)
        lsum[reg] += __shfl_xor(lsum[reg], off, 16);
    }
    __asm__ __volatile__("s_waitcnt lgkmcnt(0)" ::: "memory");
    f32x4 o[2] = {(f32x4){0.f,0.f,0.f,0.f}, (f32x4){0.f,0.f,0.f,0.f}};
#pragma unroll
    for (int ks = 0; ks < 8; ks++) {
      bf16x8 pa = *(const bf16x8*)(&Pw[((ks * 4 + quad) * 16 + lr) * 8]);
#pragma unroll
      for (int e = 0; e < 2; e++) {
        bf16x8 vb = *(const bf16x8*)(&Vf[(((ks * 2 + e) * 4 + quad) * 16 + lr) * 8]);
        o[e] = __builtin_amdgcn_mfma_f32_16x16x32_bf16(pa, vb, o[e], 0, 0, 0);
      }
    }
#pragma unroll
    for (int reg = 0; reg < 4; reg++) {
      float inv = __builtin_amdgcn_rcpf(lsum[reg]);
      int i = i0 + quad * 4 + reg;
      size_t base = ((size_t)r * N + i) * D + h * KD + 2 * lr;
      unsigned gv = *(const unsigned*)(g + base);
      float r0 = o[0][reg] * inv * b2f((u16)(gv & 0xffff));
      float r1 = o[1][reg] * inv * b2f((u16)(gv >> 16));
      *(unsigned*)(og + base) = (unsigned)f2b(r0) | ((unsigned)f2b(r1) << 16);
    }
  }
}

// ---------------- Kernel 3: output projection (async-staged wo) --------------
__global__ __launch_bounds__(256) void out_kernel(
    const u16* __restrict__ og, const u16* __restrict__ wob, const float* __restrict__ bo,
    const float* __restrict__ mask, float* __restrict__ out)
{
  __shared__ __align__(16) u16 Wlds[16384];
  int tid = threadIdx.x;
  async_stage(wob, Wlds, tid);
  int wave = tid >> 6, lane = tid & 63;
  int lr = lane & 15, quad = lane >> 4;
  bf16x8 a[2][4];
#pragma unroll
  for (int mt = 0; mt < 2; mt++) {
    int arow = blockIdx.x * 128 + wave * 32 + mt * 16 + lr;
#pragma unroll
    for (int ks = 0; ks < 4; ks++)
      a[mt][ks] = *(const bf16x8*)(og + (size_t)arow * D + ks * 32 + quad * 8);
  }
  __syncthreads();
  f32x4 acc[2][2][4];
#pragma unroll
  for (int mt = 0; mt < 2; mt++)
#pragma unroll
    for (int tg = 0; tg < 2; tg++)
#pragma unroll
      for (int e = 0; e < 4; e++) acc[mt][tg][e] = (f32x4){0.f, 0.f, 0.f, 0.f};
#pragma unroll
  for (int ks = 0; ks < 4; ks++) {
#pragma unroll
    for (int tg = 0; tg < 2; tg++) {
#pragma unroll
      for (int e = 0; e < 4; e++) {
        int nrow = tg * 64 + 4 * lr + e;
        int gp = (ks * 4 + quad + (nrow & 15)) & 15;
        bf16x8 b = *(const bf16x8*)(&Wlds[nrow * 128 + gp * 8]);
        acc[0][tg][e] = __builtin_amdgcn_mfma_f32_16x16x32_bf16(a[0][ks], b, acc[0][tg][e], 0, 0, 0);
        acc[1][tg][e] = __builtin_amdgcn_mfma_f32_16x16x32_bf16(a[1][ks], b, acc[1][tg][e], 0, 0, 0);
      }
    }
  }
#pragma unroll
  for (int mt = 0; mt < 2; mt++) {
    int row0 = blockIdx.x * 128 + wave * 32 + mt * 16 + quad * 4;
#pragma unroll
    for (int tg = 0; tg < 2; tg++) {
      int c0 = tg * 64 + 4 * lr;
      float4 bo4 = *(const float4*)(bo + c0);
#pragma unroll
      for (int reg = 0; reg < 4; reg++) {
        int pos = row0 + reg;
        float m = mask[pos];
        float4 o4;
        o4.x = (acc[mt][tg][0][reg] + bo4.x) * m;
        o4.y = (acc[mt][tg][1][reg] + bo4.y) * m;
        o4.z = (acc[mt][tg][2][reg] + bo4.z) * m;
        o4.w = (acc[mt][tg][3][reg] + bo4.w) * m;
        *(float4*)(out + (size_t)pos * D + c0) = o4;
      }
    }
  }
}

extern "C" void kernel_launch(void* const* d_in, const int* in_sizes, int n_in,
                              void* d_out, int out_size, void* d_ws, size_t ws_size,
                              hipStream_t stream)
{
  const float* pa   = (const float*)d_in[0];
  const float* mask = (const float*)d_in[1];
  const float* lns  = (const float*)d_in[2];
  const float* lnb  = (const float*)d_in[3];
  const float* w2d  = (const float*)d_in[4];
  const float* wq   = (const float*)d_in[5];
  const float* wk   = (const float*)d_in[6];
  const float* wv   = (const float*)d_in[7];
  const float* wg   = (const float*)d_in[8];
  const float* bg   = (const float*)d_in[9];
  const float* wo   = (const float*)d_in[10];
  const float* bo   = (const float*)d_in[11];

  const size_t ARR = (size_t)NN * D;     // 8M elements
  u16* q  = (u16*)d_ws;
  u16* k  = q + ARR;
  u16* v  = k + ARR;
  u16* g  = v + ARR;
  u16* og = g + ARR;
  float* nbT = (float*)(og + ARR);        // NH*NN floats, TRANSPOSED [h][j][i]
  u16* wb = (u16*)(nbT + (size_t)NH * NN); // 5*16384 u16, swizzled LDS image

  prep_w_kernel<<<40, 256, 0, stream>>>(wq, wk, wv, wg, wo, wb);
  projln_kernel<<<512, 256, 0, stream>>>(pa, lns, lnb, w2d, wb, bg, q, k, v, g, nbT);
  attn_kernel<<<N * NH, 256, 0, stream>>>(q, k, v, g, nbT, mask, og);
  out_kernel<<<512, 256, 0, stream>>>(og, wb + 4 * 16384, bo, mask, (float*)d_out);
}